// Round 1
// baseline (273.006 us; speedup 1.0000x reference)
//
#include <hip/hip_runtime.h>
#include <hip/hip_bf16.h>

#define EPS 1e-5f
#define ATTN_SMEM 152448

typedef short bf16x8 __attribute__((ext_vector_type(8)));
typedef float f32x4 __attribute__((ext_vector_type(4)));

#define GL16(gp, lp) __builtin_amdgcn_global_load_lds( \
    (const __attribute__((address_space(1))) void*)(gp), \
    (__attribute__((address_space(3))) void*)(lp), 16, 0, 0)

__device__ __forceinline__ unsigned short f2bf(float f) {
  union { float f; unsigned u; } v; v.f = f;
  return (unsigned short)((v.u + 0x7FFFu + ((v.u >> 16) & 1u)) >> 16);
}

// ---------------- fp32 -> bf16 convert ----------------
__global__ void cvt_kernel(const float* __restrict__ src,
                           unsigned short* __restrict__ dst, int n) {
  int i = (blockIdx.x * blockDim.x + threadIdx.x) * 8;
  if (i >= n) return;
  float4 a = *(const float4*)(src + i);
  float4 b = *(const float4*)(src + i + 4);
  union { bf16x8 v; unsigned short u[8]; } o;
  o.u[0] = f2bf(a.x); o.u[1] = f2bf(a.y); o.u[2] = f2bf(a.z); o.u[3] = f2bf(a.w);
  o.u[4] = f2bf(b.x); o.u[5] = f2bf(b.y); o.u[6] = f2bf(b.z); o.u[7] = f2bf(b.w);
  *(bf16x8*)(dst + i) = o.v;
}

// ---------------- W (K x N) fp32 -> W^T (N x K) bf16, optional scale ----------------
__global__ void wtrans_kernel(const float* __restrict__ W,
                              unsigned short* __restrict__ Wt, float scale) {
  __shared__ float tile[32][33];
  int n0 = blockIdx.x * 32, k0 = blockIdx.y * 32;
  int c = threadIdx.x & 31, r0 = threadIdx.x >> 5;
  #pragma unroll
  for (int rr = 0; rr < 32; rr += 8)
    tile[r0 + rr][c] = W[(k0 + r0 + rr) * 512 + n0 + c];
  __syncthreads();
  #pragma unroll
  for (int rr = 0; rr < 32; rr += 8)
    Wt[(n0 + r0 + rr) * 512 + k0 + c] = f2bf(tile[c][r0 + rr] * scale);
}

// ---------------- per-(b,q) stoich row stats: sum(P), sum(N), sum(P^2), sum(N^2) ----------------
__global__ void frac_stats_kernel(const float* __restrict__ frac,
                                  float* __restrict__ fstats) {
  int wid = (int)((blockIdx.x * blockDim.x + threadIdx.x) >> 6);
  int ln = threadIdx.x & 63;
  if (wid >= 8192) return;
  int b = wid >> 10, q = wid & 1023;
  const float* fr = frac + b * 1024;
  float fq = fr[q];
  float sp = 0.f, sn = 0.f, sp2 = 0.f, sn2 = 0.f;
  for (int i = ln; i < 1024; i += 64) {
    float f = fr[i];
    float dm = (f - fq) * (fq * f);
    float p = fmaxf(dm, 0.f), nn = fminf(dm, 0.f);
    sp += p; sn += nn; sp2 += p * p; sn2 += nn * nn;
  }
  #pragma unroll
  for (int m = 32; m; m >>= 1) {
    sp += __shfl_xor(sp, m); sn += __shfl_xor(sn, m);
    sp2 += __shfl_xor(sp2, m); sn2 += __shfl_xor(sn2, m);
  }
  if (ln == 0) {
    float4 o; o.x = sp; o.y = sn; o.z = sp2; o.w = sn2;
    *(float4*)(fstats + (size_t)wid * 4) = o;
  }
}

// ---------------- bf16 MFMA GEMM:  C(M x 512) = A(M x 512) * W^T(rows=n)  + bias ----------------
// MODE 0: bf16 out scattered to (b,h,t,d)   [Q, K]
// MODE 1: bf16 out scattered to (b,h,d,t)   [V transposed]
// MODE 2: fp32 out linear (m, n)            [final output]
template <int MODE>
__global__ __launch_bounds__(256) void gemm_kernel(
    const unsigned short* __restrict__ A,
    const unsigned short* __restrict__ Bt,
    const float* __restrict__ bias, float bscale,
    void* __restrict__ out) {
  __shared__ unsigned short Al[2][128 * 32];
  __shared__ unsigned short Bl[2][128 * 32];
  const int tid = threadIdx.x, ln = tid & 63, wv = tid >> 6;
  const int m0 = blockIdx.y * 128, n0 = blockIdx.x * 128;
  const int wr = wv >> 1, wc = wv & 1;

  auto stage = [&](int kt, int buf) {
    int kb = kt * 32;
    #pragma unroll
    for (int u = 0; u < 2; ++u) {
      int n = tid + u * 256;
      int Lrow = n >> 2, kcs = n & 3;
      int kc = kcs ^ (Lrow & 3);  // chunk swizzle (involution)
      GL16(A + (size_t)(m0 + Lrow) * 512 + kb + kc * 8, &Al[buf][n * 8]);
      GL16(Bt + (size_t)(n0 + Lrow) * 512 + kb + kc * 8, &Bl[buf][n * 8]);
    }
  };

  f32x4 acc[4][4] = {};
  stage(0, 0);
  for (int kt = 0; kt < 16; ++kt) {
    __syncthreads();                 // drains staging of tile kt (vmcnt0 + barrier)
    if (kt < 15) stage(kt + 1, (kt + 1) & 1);
    const unsigned short* a_ = Al[kt & 1];
    const unsigned short* b_ = Bl[kt & 1];
    const int kc = ln >> 4;
    bf16x8 afr[4], bfr[4];
    #pragma unroll
    for (int m = 0; m < 4; ++m) {
      int r = wr * 64 + m * 16 + (ln & 15);
      afr[m] = *(const bf16x8*)(a_ + r * 32 + ((kc ^ (r & 3)) * 8));
    }
    #pragma unroll
    for (int n = 0; n < 4; ++n) {
      int r = wc * 64 + n * 16 + (ln & 15);
      bfr[n] = *(const bf16x8*)(b_ + r * 32 + ((kc ^ (r & 3)) * 8));
    }
    #pragma unroll
    for (int m = 0; m < 4; ++m)
      #pragma unroll
      for (int n = 0; n < 4; ++n)
        acc[m][n] = __builtin_amdgcn_mfma_f32_16x16x32_bf16(afr[m], bfr[n], acc[m][n], 0, 0, 0);
  }

  #pragma unroll
  for (int m = 0; m < 4; ++m) {
    #pragma unroll
    for (int n = 0; n < 4; ++n) {
      int gm0 = m0 + wr * 64 + m * 16 + (ln >> 4) * 4;
      int gn = n0 + wc * 64 + n * 16 + (ln & 15);
      float bvv = bias[gn] * bscale;
      if constexpr (MODE == 2) {
        float* o = (float*)out;
        #pragma unroll
        for (int i = 0; i < 4; ++i)
          o[(size_t)(gm0 + i) * 512 + gn] = acc[m][n][i] + bvv;
      } else if constexpr (MODE == 0) {
        unsigned short* o = (unsigned short*)out;
        int h = gn >> 6, d = gn & 63;
        #pragma unroll
        for (int i = 0; i < 4; ++i) {
          int gm = gm0 + i;
          int b = gm >> 10, t = gm & 1023;
          o[(size_t)((b * 8 + h) * 1024 + t) * 64 + d] = f2bf(acc[m][n][i] + bvv);
        }
      } else {  // MODE 1: V^T  (b,h,d,t)
        unsigned short* o = (unsigned short*)out;
        int h = gn >> 6, d = gn & 63;
        int b = gm0 >> 10, t = gm0 & 1023;
        ushort4 pk;
        pk.x = f2bf(acc[m][n][0] + bvv);
        pk.y = f2bf(acc[m][n][1] + bvv);
        pk.z = f2bf(acc[m][n][2] + bvv);
        pk.w = f2bf(acc[m][n][3] + bvv);
        *(ushort4*)(o + (size_t)((b * 8 + h) * 64 + d) * 1024 + t) = pk;
      }
    }
  }
}

// ---------------- fused attention: one block per (b,h, 32-query tile) ----------------
// LDS: S[32][1024] fp32 (scores, later bf16 P in-place, swizzled)
//      Kt[2][64][64] bf16 (staged K tiles, chunk-swizzled)
__global__ __launch_bounds__(512) void attn_kernel(
    const unsigned short* __restrict__ Qh,   // (b,h,t,d) bf16, pre-scaled by 1/8
    const unsigned short* __restrict__ Kh,   // (b,h,t,d) bf16
    const unsigned short* __restrict__ Vt,   // (b,h,d,t) bf16
    unsigned short* __restrict__ attnO,      // (b,t,h*64+d) bf16
    const float* __restrict__ frac,
    const float* __restrict__ fstats,
    const float* __restrict__ alpha_pos,
    const float* __restrict__ alpha_neg,
    const float* __restrict__ gamma_p,
    const float* __restrict__ delta_p,
    const int* __restrict__ afb_p) {
  extern __shared__ char smem[];
  float* S = (float*)smem;                                  // 131072 B
  unsigned short* Kt = (unsigned short*)(smem + 131072);    // 16384 B
  float* fk = (float*)(smem + 147456);                      // 4096 B
  float* sumL = (float*)(smem + 151552);
  float* sumL2 = (float*)(smem + 151680);
  float* coefA = (float*)(smem + 151808);
  float* coefB = (float*)(smem + 151936);
  float* rowRcp = (float*)(smem + 152064);
  float* fqs = (float*)(smem + 152192);

  const int bh = blockIdx.y, b = bh >> 3, h = bh & 7;
  const int t0 = blockIdx.x * 32;
  const int tid = threadIdx.x, ln = tid & 63, wv = tid >> 6;

  fk[tid] = frac[b * 1024 + tid];
  fk[tid + 512] = frac[b * 1024 + 512 + tid];
  if (tid < 32) {
    sumL[tid] = 0.f; sumL2[tid] = 0.f;
    fqs[tid] = frac[b * 1024 + t0 + tid];
    const float ap = alpha_pos[h], an = alpha_neg[h];
    float4 st = *(const float4*)(fstats + (size_t)(b * 1024 + t0 + tid) * 4);
    float msum = ap * st.x + an * st.y;
    float msq = ap * ap * st.z + an * an * st.w;
    float mean = msum * (1.f / 1024.f);
    float var = fmaxf((msq - 1024.f * mean * mean) * (1.f / 1023.f), 0.f);
    coefB[tid] = (*afb_p) ? ((*delta_p) / (sqrtf(var) + EPS)) : 0.f;
  }

  // wave roles for S production: qt = which 16 query rows, kt16 = which 16-key strip
  const int qt = wv >> 2, kt16 = wv & 3;
  const int qrow = t0 + qt * 16 + (ln & 15);
  const unsigned short* qptr = Qh + (size_t)(bh * 1024 + qrow) * 64 + (ln >> 4) * 8;
  bf16x8 aq0 = *(const bf16x8*)(qptr);
  bf16x8 aq1 = *(const bf16x8*)(qptr + 32);

  auto stageK = [&](int kt, int buf) {
    int row = tid >> 3, kcs = tid & 7;
    int kc = kcs ^ (row & 7);  // involution swizzle
    GL16(Kh + (size_t)(bh * 1024 + kt * 64 + row) * 64 + kc * 8,
         Kt + buf * 4096 + tid * 8);
  };

  stageK(0, 0);
  float sA[4] = {0.f, 0.f, 0.f, 0.f}, sA2[4] = {0.f, 0.f, 0.f, 0.f};
  const int krow = kt16 * 16 + (ln & 15);
  for (int kt = 0; kt < 16; ++kt) {
    __syncthreads();  // staging of tile kt complete for all waves
    if (kt < 15) stageK(kt + 1, (kt + 1) & 1);
    const unsigned short* kb_ = Kt + (kt & 1) * 4096;
    int kc0 = (ln >> 4) ^ (krow & 7);
    int kc1 = ((ln >> 4) + 4) ^ (krow & 7);
    bf16x8 bk0 = *(const bf16x8*)(kb_ + krow * 64 + kc0 * 8);
    bf16x8 bk1 = *(const bf16x8*)(kb_ + krow * 64 + kc1 * 8);
    f32x4 acc = {0.f, 0.f, 0.f, 0.f};
    acc = __builtin_amdgcn_mfma_f32_16x16x32_bf16(aq0, bk0, acc, 0, 0, 0);
    acc = __builtin_amdgcn_mfma_f32_16x16x32_bf16(aq1, bk1, acc, 0, 0, 0);
    int scol = kt * 64 + kt16 * 16 + (ln & 15);
    float* srow = S + (size_t)(qt * 16 + (ln >> 4) * 4) * 1024 + scol;
    #pragma unroll
    for (int i = 0; i < 4; ++i) {
      float vv = acc[i];
      sA[i] += vv; sA2[i] += vv * vv;
      srow[i * 1024] = vv;
    }
  }
  #pragma unroll
  for (int m = 1; m < 16; m <<= 1) {
    #pragma unroll
    for (int i = 0; i < 4; ++i) {
      sA[i] += __shfl_xor(sA[i], m);
      sA2[i] += __shfl_xor(sA2[i], m);
    }
  }
  if ((ln & 15) == 0) {
    int r = qt * 16 + (ln >> 4) * 4;
    #pragma unroll
    for (int i = 0; i < 4; ++i) {
      atomicAdd(&sumL[r + i], sA[i]);
      atomicAdd(&sumL2[r + i], sA2[i]);
    }
  }
  __syncthreads();
  if (tid < 32) {
    float mean = sumL[tid] * (1.f / 1024.f);
    float var = fmaxf((sumL2[tid] - 1024.f * mean * mean) * (1.f / 1023.f), 0.f);
    coefA[tid] = (*gamma_p) / (sqrtf(var) + EPS);
  }
  __syncthreads();

  // phase 3: per-row score transform + softmax numerator, bf16 P written in-place (swizzled)
  {
    const float ap_ = alpha_pos[h], an_ = alpha_neg[h];
    for (int rr = 0; rr < 4; ++rr) {
      const int r = wv * 4 + rr;
      const float fq = fqs[r], cA = coefA[r], cB = coefB[r];
      float* srow = S + (size_t)r * 1024;
      float vmax = -3.0e38f;
      #pragma unroll 4
      for (int i = 0; i < 16; ++i) {
        int c = ln + i * 64;
        float l = srow[c], f = fk[c];
        float dm = (f - fq) * (fq * f);
        float s = ap_ * fmaxf(dm, 0.f) + an_ * fminf(dm, 0.f);
        float sc = cA * l + cB * s;
        srow[c] = sc;
        vmax = fmaxf(vmax, sc);
      }
      #pragma unroll
      for (int m = 1; m < 64; m <<= 1) vmax = fmaxf(vmax, __shfl_xor(vmax, m));
      float psum = 0.f;
      char* prow = (char*)S + (size_t)r * 4096;
      int sw = (r & 7) << 4;
      #pragma unroll 4
      for (int i = 0; i < 16; ++i) {
        int c = ln + i * 64;
        float p = __expf(srow[c] - vmax);
        psum += p;
        *(unsigned short*)(prow + ((2 * c) ^ sw)) = f2bf(p);
      }
      #pragma unroll
      for (int m = 1; m < 64; m <<= 1) psum += __shfl_xor(psum, m);
      if (ln == 0) rowRcp[r] = 1.f / psum;
    }
  }
  __syncthreads();

  // phase 4: O = P * V via MFMA; wave -> (16 query rows, 16 output dims)
  {
    const int qt2 = wv >> 2, dt = wv & 3;
    const int prow = qt2 * 16 + (ln & 15);
    const char* pbase = (char*)S + (size_t)prow * 4096;
    const int sw = (prow & 7) << 4;
    const unsigned short* vbase =
        Vt + (size_t)(bh * 64 + dt * 16 + (ln & 15)) * 1024 + (ln >> 4) * 8;
    f32x4 o0 = {0.f, 0.f, 0.f, 0.f}, o1 = o0, o2 = o0, o3 = o0;
    #pragma unroll
    for (int s = 0; s < 8; ++s) {
      int base = s * 32;
      bf16x8 pa0 = *(const bf16x8*)(pbase + (((base)*2 + (ln >> 4) * 16) ^ sw));
      bf16x8 vv0 = *(const bf16x8*)(vbase + base);
      o0 = __builtin_amdgcn_mfma_f32_16x16x32_bf16(pa0, vv0, o0, 0, 0, 0);
      bf16x8 pa1 = *(const bf16x8*)(pbase + (((base + 256) * 2 + (ln >> 4) * 16) ^ sw));
      bf16x8 vv1 = *(const bf16x8*)(vbase + base + 256);
      o1 = __builtin_amdgcn_mfma_f32_16x16x32_bf16(pa1, vv1, o1, 0, 0, 0);
      bf16x8 pa2 = *(const bf16x8*)(pbase + (((base + 512) * 2 + (ln >> 4) * 16) ^ sw));
      bf16x8 vv2 = *(const bf16x8*)(vbase + base + 512);
      o2 = __builtin_amdgcn_mfma_f32_16x16x32_bf16(pa2, vv2, o2, 0, 0, 0);
      bf16x8 pa3 = *(const bf16x8*)(pbase + (((base + 768) * 2 + (ln >> 4) * 16) ^ sw));
      bf16x8 vv3 = *(const bf16x8*)(vbase + base + 768);
      o3 = __builtin_amdgcn_mfma_f32_16x16x32_bf16(pa3, vv3, o3, 0, 0, 0);
    }
    f32x4 oo = (o0 + o1) + (o2 + o3);
    #pragma unroll
    for (int i = 0; i < 4; ++i) {
      int r = qt2 * 16 + (ln >> 4) * 4 + i;
      float val = oo[i] * rowRcp[r];
      attnO[(size_t)(b * 1024 + t0 + r) * 512 + h * 64 + dt * 16 + (ln & 15)] = f2bf(val);
    }
  }
}

extern "C" void kernel_launch(void* const* d_in, const int* in_sizes, int n_in,
                              void* d_out, int out_size, void* d_ws, size_t ws_size,
                              hipStream_t stream) {
  const float* q = (const float*)d_in[0];
  const float* k = (const float*)d_in[1];
  const float* v = (const float*)d_in[2];
  const float* frac = (const float*)d_in[3];
  const float* Wq = (const float*)d_in[4];
  const float* bq = (const float*)d_in[5];
  const float* Wk = (const float*)d_in[6];
  const float* bk = (const float*)d_in[7];
  const float* Wv = (const float*)d_in[8];
  const float* bv = (const float*)d_in[9];
  const float* Wo = (const float*)d_in[10];
  const float* bo = (const float*)d_in[11];
  const float* ap = (const float*)d_in[12];
  const float* an = (const float*)d_in[13];
  const float* gm = (const float*)d_in[14];
  const float* dl = (const float*)d_in[15];
  const int* afb = (const int*)d_in[16];

  char* ws = (char*)d_ws;
  unsigned short* qb = (unsigned short*)(ws + 0);            // 8 MB  query bf16
  unsigned short* kb = (unsigned short*)(ws + 8388608);      // 8 MB  key bf16
  unsigned short* vb = (unsigned short*)(ws + 16777216);     // 8 MB  value bf16
  unsigned short* wqT = (unsigned short*)(ws + 25165824);    // 512 KB
  unsigned short* wkT = (unsigned short*)(ws + 25690112);
  unsigned short* wvT = (unsigned short*)(ws + 26214400);
  unsigned short* woT = (unsigned short*)(ws + 26738688);
  unsigned short* Qh = (unsigned short*)(ws + 27262976);     // 8 MB  (b,h,t,d)
  unsigned short* Kh = (unsigned short*)(ws + 35651584);     // 8 MB
  unsigned short* Vt = (unsigned short*)(ws + 44040192);     // 8 MB  (b,h,d,t)
  unsigned short* aO = (unsigned short*)(ws + 52428800);     // 8 MB  attn out bf16
  float* fst = (float*)(ws + 60817408);                      // 128 KB stoich stats

  hipFuncSetAttribute((const void*)attn_kernel,
                      hipFuncAttributeMaxDynamicSharedMemorySize, ATTN_SMEM);

  cvt_kernel<<<2048, 256, 0, stream>>>(q, qb, 4194304);
  cvt_kernel<<<2048, 256, 0, stream>>>(k, kb, 4194304);
  cvt_kernel<<<2048, 256, 0, stream>>>(v, vb, 4194304);
  wtrans_kernel<<<dim3(16, 16), 256, 0, stream>>>(Wq, wqT, 0.125f);  // fold 1/sqrt(64)
  wtrans_kernel<<<dim3(16, 16), 256, 0, stream>>>(Wk, wkT, 1.0f);
  wtrans_kernel<<<dim3(16, 16), 256, 0, stream>>>(Wv, wvT, 1.0f);
  wtrans_kernel<<<dim3(16, 16), 256, 0, stream>>>(Wo, woT, 1.0f);
  frac_stats_kernel<<<2048, 256, 0, stream>>>(frac, fst);
  gemm_kernel<0><<<dim3(4, 64), 256, 0, stream>>>(qb, wqT, bq, 0.125f, (void*)Qh);
  gemm_kernel<0><<<dim3(4, 64), 256, 0, stream>>>(kb, wkT, bk, 1.0f, (void*)Kh);
  gemm_kernel<1><<<dim3(4, 64), 256, 0, stream>>>(vb, wvT, bv, 1.0f, (void*)Vt);
  attn_kernel<<<dim3(32, 64), 512, ATTN_SMEM, stream>>>(Qh, Kh, Vt, aO, frac, fst,
                                                        ap, an, gm, dl, afb);
  gemm_kernel<2><<<dim3(4, 64), 256, 0, stream>>>(aO, woT, bo, 1.0f, d_out);
}

// Round 2
// 222.263 us; speedup vs baseline: 1.2283x; 1.2283x over previous
//
#include <hip/hip_runtime.h>
#include <hip/hip_bf16.h>

#define EPS 1e-5f
#define ATTN_SMEM 74240

typedef short bf16x8 __attribute__((ext_vector_type(8)));
typedef float f32x4 __attribute__((ext_vector_type(4)));

#define GL16(gp, lp) __builtin_amdgcn_global_load_lds( \
    (const __attribute__((address_space(1))) void*)(gp), \
    (__attribute__((address_space(3))) void*)(lp), 16, 0, 0)

__device__ __forceinline__ unsigned short f2bf(float f) {
  union { float f; unsigned u; } v; v.f = f;
  return (unsigned short)((v.u + 0x7FFFu + ((v.u >> 16) & 1u)) >> 16);
}

// ---------------- fp32 -> bf16 convert ----------------
__global__ void cvt_kernel(const float* __restrict__ src,
                           unsigned short* __restrict__ dst, int n) {
  int i = (blockIdx.x * blockDim.x + threadIdx.x) * 8;
  if (i >= n) return;
  float4 a = *(const float4*)(src + i);
  float4 b = *(const float4*)(src + i + 4);
  union { bf16x8 v; unsigned short u[8]; } o;
  o.u[0] = f2bf(a.x); o.u[1] = f2bf(a.y); o.u[2] = f2bf(a.z); o.u[3] = f2bf(a.w);
  o.u[4] = f2bf(b.x); o.u[5] = f2bf(b.y); o.u[6] = f2bf(b.z); o.u[7] = f2bf(b.w);
  *(bf16x8*)(dst + i) = o.v;
}

// ---------------- W (K x N) fp32 -> W^T (N x K) bf16, optional scale ----------------
__global__ void wtrans_kernel(const float* __restrict__ W,
                              unsigned short* __restrict__ Wt, float scale) {
  __shared__ float tile[32][33];
  int n0 = blockIdx.x * 32, k0 = blockIdx.y * 32;
  int c = threadIdx.x & 31, r0 = threadIdx.x >> 5;
  #pragma unroll
  for (int rr = 0; rr < 32; rr += 8)
    tile[r0 + rr][c] = W[(k0 + r0 + rr) * 512 + n0 + c];
  __syncthreads();
  #pragma unroll
  for (int rr = 0; rr < 32; rr += 8)
    Wt[(n0 + r0 + rr) * 512 + k0 + c] = f2bf(tile[c][r0 + rr] * scale);
}

// ---------------- per-(b,q) stoich row stats: sum(P), sum(N), sum(P^2), sum(N^2) ----------------
__global__ void frac_stats_kernel(const float* __restrict__ frac,
                                  float* __restrict__ fstats) {
  int wid = (int)((blockIdx.x * blockDim.x + threadIdx.x) >> 6);
  int ln = threadIdx.x & 63;
  if (wid >= 8192) return;
  int b = wid >> 10, q = wid & 1023;
  const float* fr = frac + b * 1024;
  float fq = fr[q];
  float sp = 0.f, sn = 0.f, sp2 = 0.f, sn2 = 0.f;
  for (int i = ln; i < 1024; i += 64) {
    float f = fr[i];
    float dm = (f - fq) * (fq * f);
    float p = fmaxf(dm, 0.f), nn = fminf(dm, 0.f);
    sp += p; sn += nn; sp2 += p * p; sn2 += nn * nn;
  }
  #pragma unroll
  for (int m = 32; m; m >>= 1) {
    sp += __shfl_xor(sp, m); sn += __shfl_xor(sn, m);
    sp2 += __shfl_xor(sp2, m); sn2 += __shfl_xor(sn2, m);
  }
  if (ln == 0) {
    float4 o; o.x = sp; o.y = sn; o.z = sp2; o.w = sn2;
    *(float4*)(fstats + (size_t)wid * 4) = o;
  }
}

// ---------------- bf16 MFMA GEMM:  C(M x 512) = A(M x 512) * W^T(rows=n)  + bias ----------------
template <int MODE>
__global__ __launch_bounds__(256) void gemm_kernel(
    const unsigned short* __restrict__ A,
    const unsigned short* __restrict__ Bt,
    const float* __restrict__ bias, float bscale,
    void* __restrict__ out) {
  __shared__ unsigned short Al[2][128 * 32];
  __shared__ unsigned short Bl[2][128 * 32];
  const int tid = threadIdx.x, ln = tid & 63, wv = tid >> 6;
  const int m0 = blockIdx.y * 128, n0 = blockIdx.x * 128;
  const int wr = wv >> 1, wc = wv & 1;

  auto stage = [&](int kt, int buf) {
    int kb = kt * 32;
    #pragma unroll
    for (int u = 0; u < 2; ++u) {
      int n = tid + u * 256;
      int Lrow = n >> 2, kcs = n & 3;
      int kc = kcs ^ (Lrow & 3);
      GL16(A + (size_t)(m0 + Lrow) * 512 + kb + kc * 8, &Al[buf][n * 8]);
      GL16(Bt + (size_t)(n0 + Lrow) * 512 + kb + kc * 8, &Bl[buf][n * 8]);
    }
  };

  f32x4 acc[4][4] = {};
  stage(0, 0);
  for (int kt = 0; kt < 16; ++kt) {
    __syncthreads();
    if (kt < 15) stage(kt + 1, (kt + 1) & 1);
    const unsigned short* a_ = Al[kt & 1];
    const unsigned short* b_ = Bl[kt & 1];
    const int kc = ln >> 4;
    bf16x8 afr[4], bfr[4];
    #pragma unroll
    for (int m = 0; m < 4; ++m) {
      int r = wr * 64 + m * 16 + (ln & 15);
      afr[m] = *(const bf16x8*)(a_ + r * 32 + ((kc ^ (r & 3)) * 8));
    }
    #pragma unroll
    for (int n = 0; n < 4; ++n) {
      int r = wc * 64 + n * 16 + (ln & 15);
      bfr[n] = *(const bf16x8*)(b_ + r * 32 + ((kc ^ (r & 3)) * 8));
    }
    #pragma unroll
    for (int m = 0; m < 4; ++m)
      #pragma unroll
      for (int n = 0; n < 4; ++n)
        acc[m][n] = __builtin_amdgcn_mfma_f32_16x16x32_bf16(afr[m], bfr[n], acc[m][n], 0, 0, 0);
  }

  #pragma unroll
  for (int m = 0; m < 4; ++m) {
    #pragma unroll
    for (int n = 0; n < 4; ++n) {
      int gm0 = m0 + wr * 64 + m * 16 + (ln >> 4) * 4;
      int gn = n0 + wc * 64 + n * 16 + (ln & 15);
      float bvv = bias[gn] * bscale;
      if constexpr (MODE == 2) {
        float* o = (float*)out;
        #pragma unroll
        for (int i = 0; i < 4; ++i)
          o[(size_t)(gm0 + i) * 512 + gn] = acc[m][n][i] + bvv;
      } else if constexpr (MODE == 0) {
        unsigned short* o = (unsigned short*)out;
        int h = gn >> 6, d = gn & 63;
        #pragma unroll
        for (int i = 0; i < 4; ++i) {
          int gm = gm0 + i;
          int b = gm >> 10, t = gm & 1023;
          o[(size_t)((b * 8 + h) * 1024 + t) * 64 + d] = f2bf(acc[m][n][i] + bvv);
        }
      } else {  // MODE 1: V^T (b,h,d,t)
        unsigned short* o = (unsigned short*)out;
        int h = gn >> 6, d = gn & 63;
        int b = gm0 >> 10, t = gm0 & 1023;
        ushort4 pk;
        pk.x = f2bf(acc[m][n][0] + bvv);
        pk.y = f2bf(acc[m][n][1] + bvv);
        pk.z = f2bf(acc[m][n][2] + bvv);
        pk.w = f2bf(acc[m][n][3] + bvv);
        *(ushort4*)(o + (size_t)((b * 8 + h) * 64 + d) * 1024 + t) = pk;
      }
    }
  }
}

// ---------------- fused attention v2: 16 queries/block, scores in registers ----------------
// LDS: P_lds 32KB (bf16, swizzled) | Kt 2x16KB | fk 4KB | Obuf 4KB | stats
__global__ __launch_bounds__(512, 4) void attn_kernel(
    const unsigned short* __restrict__ Qh,   // (b,h,t,d) bf16, pre-scaled by 1/8
    const unsigned short* __restrict__ Kh,   // (b,h,t,d) bf16
    const unsigned short* __restrict__ Vt,   // (b,h,d,t) bf16
    unsigned short* __restrict__ attnO,      // (b,t,h*64+d) bf16
    const float* __restrict__ frac,
    const float* __restrict__ fstats,
    const float* __restrict__ alpha_pos,
    const float* __restrict__ alpha_neg,
    const float* __restrict__ gamma_p,
    const float* __restrict__ delta_p,
    const int* __restrict__ afb_p) {
  extern __shared__ char smem[];
  char* P_lds = smem;                                      // 32768
  unsigned short* Kt = (unsigned short*)(smem + 32768);    // 32768 (2 x 16K)
  float* fk = (float*)(smem + 65536);                      // 4096
  float* Obuf = (float*)(smem + 69632);                    // 4096
  float* sumL = (float*)(smem + 73728);
  float* sumL2 = (float*)(smem + 73792);
  float* sumP = (float*)(smem + 73856);
  float* rowRcp = (float*)(smem + 73920);
  float4* rowc = (float4*)(smem + 73984);                  // 256

  const int bh = blockIdx.y, b = bh >> 3, h = bh & 7;
  const int t0 = blockIdx.x * 16;
  const int tid = threadIdx.x, ln = tid & 63, wv = tid >> 6;
  const int g = ln >> 4, lm = ln & 15;

  fk[tid] = frac[b * 1024 + tid];
  fk[tid + 512] = frac[b * 1024 + 512 + tid];
  Obuf[tid] = 0.f; Obuf[tid + 512] = 0.f;
  if (tid < 16) { sumL[tid] = 0.f; sumL2[tid] = 0.f; sumP[tid] = 0.f; }

  // Q fragments (all waves read the same 16 query rows)
  const unsigned short* qptr = Qh + (size_t)(bh * 1024 + t0 + lm) * 64 + g * 8;
  bf16x8 aq0 = *(const bf16x8*)(qptr);
  bf16x8 aq1 = *(const bf16x8*)(qptr + 32);

  auto stageK = [&](int kt, int buf) {
    #pragma unroll
    for (int u = 0; u < 2; ++u) {
      int n = tid + u * 512;
      int row = n >> 3, kc = (n & 7) ^ (row & 7);  // source-side chunk swizzle
      GL16(Kh + (size_t)(bh * 1024 + kt * 128 + row) * 64 + kc * 8,
           Kt + buf * 8192 + n * 8);
    }
  };

  // ---- phase 1: QK^T into registers, 8 x 128-key tiles, double-buffered ----
  f32x4 sc[8] = {};
  stageK(0, 0);
  const int krow = wv * 16 + lm;
  #pragma unroll
  for (int kt = 0; kt < 8; ++kt) {
    __syncthreads();
    if (kt < 7) stageK(kt + 1, (kt + 1) & 1);
    const unsigned short* kb_ = Kt + (kt & 1) * 8192;
    int kc0 = g ^ (krow & 7);
    int kc1 = (g + 4) ^ (krow & 7);
    bf16x8 bk0 = *(const bf16x8*)(kb_ + krow * 64 + kc0 * 8);
    bf16x8 bk1 = *(const bf16x8*)(kb_ + krow * 64 + kc1 * 8);
    sc[kt] = __builtin_amdgcn_mfma_f32_16x16x32_bf16(aq0, bk0, sc[kt], 0, 0, 0);
    sc[kt] = __builtin_amdgcn_mfma_f32_16x16x32_bf16(aq1, bk1, sc[kt], 0, 0, 0);
  }

  // ---- phase 2: row stats (sum, sumsq) from registers ----
  float sL[4] = {0, 0, 0, 0}, sL2[4] = {0, 0, 0, 0};
  #pragma unroll
  for (int t = 0; t < 8; ++t)
    #pragma unroll
    for (int i = 0; i < 4; ++i) { float v = sc[t][i]; sL[i] += v; sL2[i] += v * v; }
  #pragma unroll
  for (int m = 1; m < 16; m <<= 1)
    #pragma unroll
    for (int i = 0; i < 4; ++i) {
      sL[i] += __shfl_xor(sL[i], m);
      sL2[i] += __shfl_xor(sL2[i], m);
    }
  if (lm == 0) {
    #pragma unroll
    for (int i = 0; i < 4; ++i) {
      atomicAdd(&sumL[g * 4 + i], sL[i]);
      atomicAdd(&sumL2[g * 4 + i], sL2[i]);
    }
  }
  __syncthreads();
  if (tid < 16) {
    int r = tid;
    float mul_ = sumL[r] * (1.f / 1024.f);
    float varl = fmaxf((sumL2[r] - 1024.f * mul_ * mul_) * (1.f / 1023.f), 0.f);
    float cA = (*gamma_p) / (sqrtf(varl) + EPS);
    float ap = alpha_pos[h], an = alpha_neg[h];
    float4 st = *(const float4*)(fstats + (size_t)(b * 1024 + t0 + r) * 4);
    float msum = ap * st.x + an * st.y;
    float msq = ap * ap * st.z + an * an * st.w;
    float mus = msum * (1.f / 1024.f);
    float vars = fmaxf((msq - 1024.f * mus * mus) * (1.f / 1023.f), 0.f);
    float cB = (*afb_p) ? ((*delta_p) / (sqrtf(vars) + EPS)) : 0.f;
    float4 rc;
    rc.x = frac[b * 1024 + t0 + r];   // fq
    rc.y = cA;
    rc.z = cB;
    rc.w = cA * mul_ + cB * mus;      // per-row shift (softmax-invariant part)
    rowc[r] = rc;
  }
  __syncthreads();

  // ---- phase 3: transform + exp in registers, write bf16 P to swizzled LDS ----
  {
    const float ap_ = alpha_pos[h], an_ = alpha_neg[h];
    float4 rc0 = rowc[g * 4 + 0], rc1 = rowc[g * 4 + 1];
    float4 rc2 = rowc[g * 4 + 2], rc3 = rowc[g * 4 + 3];
    float psum[4] = {0, 0, 0, 0};
    #pragma unroll
    for (int t = 0; t < 8; ++t) {
      int c = t * 128 + wv * 16 + lm;
      float f = fk[c];
      #pragma unroll
      for (int i = 0; i < 4; ++i) {
        float4 rc = (i == 0) ? rc0 : (i == 1) ? rc1 : (i == 2) ? rc2 : rc3;
        int r = g * 4 + i;
        float dm = (f - rc.x) * (rc.x * f);
        float s = ap_ * fmaxf(dm, 0.f) + an_ * fminf(dm, 0.f);
        float e = __expf(rc.y * sc[t][i] + rc.z * s - rc.w);
        psum[i] += e;
        int sw = ((r & 7) << 4) ^ ((r & 8) << 2);
        *(unsigned short*)(P_lds + r * 2048 + ((2 * c) ^ sw)) = f2bf(e);
      }
    }
    #pragma unroll
    for (int m = 1; m < 16; m <<= 1)
      #pragma unroll
      for (int i = 0; i < 4; ++i) psum[i] += __shfl_xor(psum[i], m);
    if (lm == 0) {
      #pragma unroll
      for (int i = 0; i < 4; ++i) atomicAdd(&sumP[g * 4 + i], psum[i]);
    }
  }
  __syncthreads();
  if (tid < 16) rowRcp[tid] = 1.f / sumP[tid];

  // ---- phase 4: O = P*V via MFMA; wave = (16 dims, 512-key half) ----
  {
    const int dt = wv & 3, kh = wv >> 2;
    const int r = lm;
    const int sw = ((r & 7) << 4) ^ ((r & 8) << 2);
    const char* pb = P_lds + r * 2048;
    const unsigned short* vbase =
        Vt + (size_t)(bh * 64 + dt * 16 + lm) * 1024 + kh * 512 + g * 8;
    f32x4 o0 = {0, 0, 0, 0}, o1 = o0, o2 = o0, o3 = o0;
    #pragma unroll
    for (int s = 0; s < 4; ++s) {
      int kbyte = kh * 1024 + s * 256 + g * 16;
      bf16x8 pa0 = *(const bf16x8*)(pb + ((kbyte) ^ sw));
      bf16x8 vv0 = *(const bf16x8*)(vbase + s * 128);
      o0 = __builtin_amdgcn_mfma_f32_16x16x32_bf16(pa0, vv0, o0, 0, 0, 0);
      bf16x8 pa1 = *(const bf16x8*)(pb + ((kbyte + 64) ^ sw));
      bf16x8 vv1 = *(const bf16x8*)(vbase + s * 128 + 32);
      o1 = __builtin_amdgcn_mfma_f32_16x16x32_bf16(pa1, vv1, o1, 0, 0, 0);
      bf16x8 pa2 = *(const bf16x8*)(pb + ((kbyte + 128) ^ sw));
      bf16x8 vv2 = *(const bf16x8*)(vbase + s * 128 + 64);
      o2 = __builtin_amdgcn_mfma_f32_16x16x32_bf16(pa2, vv2, o2, 0, 0, 0);
      bf16x8 pa3 = *(const bf16x8*)(pb + ((kbyte + 192) ^ sw));
      bf16x8 vv3 = *(const bf16x8*)(vbase + s * 128 + 96);
      o3 = __builtin_amdgcn_mfma_f32_16x16x32_bf16(pa3, vv3, o3, 0, 0, 0);
    }
    f32x4 oo = (o0 + o1) + (o2 + o3);
    #pragma unroll
    for (int i = 0; i < 4; ++i)
      atomicAdd(&Obuf[(g * 4 + i) * 64 + dt * 16 + lm], oo[i]);
  }
  __syncthreads();

  // ---- epilogue: normalize + store bf16 ----
  {
    int q = tid >> 5, d2 = (tid & 31) * 2;
    float rcp = rowRcp[q];
    float2 v = *(const float2*)(Obuf + q * 64 + d2);
    unsigned outw = ((unsigned)f2bf(v.y * rcp) << 16) | f2bf(v.x * rcp);
    *(unsigned*)(attnO + (size_t)(b * 1024 + t0 + q) * 512 + h * 64 + d2) = outw;
  }
}

extern "C" void kernel_launch(void* const* d_in, const int* in_sizes, int n_in,
                              void* d_out, int out_size, void* d_ws, size_t ws_size,
                              hipStream_t stream) {
  const float* q = (const float*)d_in[0];
  const float* k = (const float*)d_in[1];
  const float* v = (const float*)d_in[2];
  const float* frac = (const float*)d_in[3];
  const float* Wq = (const float*)d_in[4];
  const float* bq = (const float*)d_in[5];
  const float* Wk = (const float*)d_in[6];
  const float* bk = (const float*)d_in[7];
  const float* Wv = (const float*)d_in[8];
  const float* bv = (const float*)d_in[9];
  const float* Wo = (const float*)d_in[10];
  const float* bo = (const float*)d_in[11];
  const float* ap = (const float*)d_in[12];
  const float* an = (const float*)d_in[13];
  const float* gm = (const float*)d_in[14];
  const float* dl = (const float*)d_in[15];
  const int* afb = (const int*)d_in[16];

  char* ws = (char*)d_ws;
  unsigned short* qb = (unsigned short*)(ws + 0);
  unsigned short* kb = (unsigned short*)(ws + 8388608);
  unsigned short* vb = (unsigned short*)(ws + 16777216);
  unsigned short* wqT = (unsigned short*)(ws + 25165824);
  unsigned short* wkT = (unsigned short*)(ws + 25690112);
  unsigned short* wvT = (unsigned short*)(ws + 26214400);
  unsigned short* woT = (unsigned short*)(ws + 26738688);
  unsigned short* Qh = (unsigned short*)(ws + 27262976);
  unsigned short* Kh = (unsigned short*)(ws + 35651584);
  unsigned short* Vt = (unsigned short*)(ws + 44040192);
  unsigned short* aO = (unsigned short*)(ws + 52428800);
  float* fst = (float*)(ws + 60817408);

  hipFuncSetAttribute((const void*)attn_kernel,
                      hipFuncAttributeMaxDynamicSharedMemorySize, ATTN_SMEM);

  cvt_kernel<<<2048, 256, 0, stream>>>(q, qb, 4194304);
  cvt_kernel<<<2048, 256, 0, stream>>>(k, kb, 4194304);
  cvt_kernel<<<2048, 256, 0, stream>>>(v, vb, 4194304);
  wtrans_kernel<<<dim3(16, 16), 256, 0, stream>>>(Wq, wqT, 0.125f);
  wtrans_kernel<<<dim3(16, 16), 256, 0, stream>>>(Wk, wkT, 1.0f);
  wtrans_kernel<<<dim3(16, 16), 256, 0, stream>>>(Wv, wvT, 1.0f);
  wtrans_kernel<<<dim3(16, 16), 256, 0, stream>>>(Wo, woT, 1.0f);
  frac_stats_kernel<<<2048, 256, 0, stream>>>(frac, fst);
  gemm_kernel<0><<<dim3(4, 64), 256, 0, stream>>>(qb, wqT, bq, 0.125f, (void*)Qh);
  gemm_kernel<0><<<dim3(4, 64), 256, 0, stream>>>(kb, wkT, bk, 1.0f, (void*)Kh);
  gemm_kernel<1><<<dim3(4, 64), 256, 0, stream>>>(vb, wvT, bv, 1.0f, (void*)Vt);
  attn_kernel<<<dim3(64, 64), 512, ATTN_SMEM, stream>>>(Qh, Kh, Vt, aO, frac, fst,
                                                        ap, an, gm, dl, afb);
  gemm_kernel<2><<<dim3(4, 64), 256, 0, stream>>>(aO, woT, bo, 1.0f, d_out);
}